// Round 5
// baseline (291.802 us; speedup 1.0000x reference)
//
#include <hip/hip_runtime.h>

// R5 = ABLATION ROUND. Real kernel = R3 structure (best measured, 103us) with
// R4's XOR swizzle (proven 0-conflict). Plus 4 probe variants (template<V>)
// that write nothing to d_out and each ablate one candidate bottleneck:
//   V0 real | V1 no-store | V2 no-store+linear-gather | V3 no-store+const-B
//   V4 no-store+no-loop-barriers
// Per-dispatch rocprof durations of V1..V4 vs V0 identify the stall.

#define NTA   65536
#define DIM_O 512
#define NMAXD 512
#define NSPE  4
#define BM    64
#define BK    64

typedef __attribute__((ext_vector_type(4))) float  f32x4;
typedef __attribute__((ext_vector_type(8))) short  bf16x8;
typedef __attribute__((ext_vector_type(4))) short  bf16x4;

__device__ __forceinline__ short f2bf(float f) {
    unsigned u = __builtin_bit_cast(unsigned, f);
    u += 0x7FFFu + ((u >> 16) & 1u);
    return (short)(u >> 16);
}

__global__ void build_lists_kernel(const int* __restrict__ sym,
                                   int* __restrict__ counts,
                                   int* __restrict__ lists) {
    int i = blockIdx.x * 256 + threadIdx.x;
    int s = sym[i];
    int lane = threadIdx.x & 63;
    #pragma unroll
    for (int spe = 0; spe < NSPE; ++spe) {
        unsigned long long m = __ballot(s == spe);
        if (m == 0ull) continue;
        int leader = __ffsll(m) - 1;
        int base = 0;
        if (lane == leader) base = atomicAdd(&counts[spe], __popcll(m));
        base = __shfl(base, leader);
        if (s == spe) {
            int pos = __popcll(m & ((1ull << lane) - 1ull));
            lists[spe * NTA + base + pos] = i;
        }
    }
}

__global__ void pack_w_kernel(const float* __restrict__ W, short* __restrict__ Wp,
                              int* __restrict__ counts) {
    if (blockIdx.x == 0 && threadIdx.x < NSPE) counts[threadIdx.x] = 0;
    int idx = blockIdx.x * 256 + threadIdx.x;
    int j  = idx & 7;
    int l  = (idx >> 3) & 63;
    int nb = (idx >> 9) & 31;
    int kb = (idx >> 14) & 15;
    int s  = idx >> 18;
    int k = kb * 32 + (l >> 4) * 8 + j;
    int n = nb * 16 + (l & 15);
    Wp[idx] = f2bf(W[((size_t)s * DIM_O + k) * NMAXD + n]);
}

template<int V>
__global__ __launch_bounds__(512, 4)
void gemm_tpl(const float* __restrict__ rho,
              const short* __restrict__ Wp,
              const float* __restrict__ bias,
              const int*  __restrict__ counts,
              const int*  __restrict__ lists,
              float* __restrict__ out)
{
    const int s   = blockIdx.x & 3;
    const int mb  = blockIdx.x >> 2;
    const int cnt = counts[s];
    const int row0 = mb * BM;
    if (row0 >= cnt) return;
    int rows_here = cnt - row0; if (rows_here > BM) rows_here = BM;

    __shared__ int aidx[BM];
    __shared__ __align__(16) short Abuf[2][8 * 64 * 8];

    const int tid  = threadIdx.x;
    const int lane = tid & 63;
    const int w    = tid >> 6;
    const int lrow = lane & 15;
    const int lgr  = lane >> 4;

    if (tid < BM) {
        if constexpr (V == 2)
            aidx[tid] = (row0 + tid) & (NTA - 1);   // linear gather probe
        else
            aidx[tid] = lists[s * NTA + row0 + ((tid < rows_here) ? tid : 0)];
    }
    __syncthreads();

    const int srow  = tid >> 3;
    const int scol8 = tid & 7;
    const float* gsrc = rho + (size_t)aidx[srow] * DIM_O + scol8 * 4;
    const int c0    = scol8 >> 1;
    const int roww  = srow ^ ((c0 & 3) << 1);
    const int dswz0 = ((c0    ) * 64 + roww) * 8 + (scol8 & 1) * 4;
    const int dswz1 = ((c0 + 4) * 64 + roww) * 8 + (scol8 & 1) * 4;

    const short* wbase = Wp + ((size_t)s * 512 + w * 4) * 512 + lane * 8;

    bf16x8 bconst;
    #pragma unroll
    for (int j = 0; j < 8; ++j) bconst[j] = (short)(lane + j);

    f32x4 acc[4][4];
    #pragma unroll
    for (int m = 0; m < 4; ++m)
        #pragma unroll
        for (int n = 0; n < 4; ++n) acc[m][n] = (f32x4)0.0f;

    f32x4 st0, st1;
    st0 = *(const f32x4*)(gsrc);
    st1 = *(const f32x4*)(gsrc + 32);
    {
        bf16x4 a, b;
        #pragma unroll
        for (int q = 0; q < 4; ++q) { a[q] = f2bf(st0[q]); b[q] = f2bf(st1[q]); }
        *(bf16x4*)&Abuf[0][dswz0] = a;
        *(bf16x4*)&Abuf[0][dswz1] = b;
    }
    __syncthreads();

    for (int kt = 0; kt < 8; ++kt) {
        const int buf = kt & 1;
        if (kt < 7) {
            st0 = *(const f32x4*)(gsrc + (kt + 1) * BK);
            st1 = *(const f32x4*)(gsrc + (kt + 1) * BK + 32);
        }
        #pragma unroll
        for (int ks = 0; ks < 2; ++ks) {
            const int kb = kt * 2 + ks;
            bf16x8 bfrag[4];
            #pragma unroll
            for (int nf = 0; nf < 4; ++nf) {
                if constexpr (V == 3) bfrag[nf] = bconst;   // const-B probe
                else bfrag[nf] = *(const bf16x8*)(wbase + (size_t)(kb * 32 + nf) * 512);
            }
            #pragma unroll
            for (int mf = 0; mf < 4; ++mf) {
                const int c = ks * 4 + lgr;
                const int r = (mf * 16 + lrow) ^ ((c & 3) << 1);
                const bf16x8 afrag = *(const bf16x8*)&Abuf[buf][(c * 64 + r) * 8];
                #pragma unroll
                for (int nf = 0; nf < 4; ++nf)
                    acc[mf][nf] = __builtin_amdgcn_mfma_f32_16x16x32_bf16(
                        afrag, bfrag[nf], acc[mf][nf], 0, 0, 0);
            }
        }
        if (kt < 7) {
            bf16x4 a, b;
            #pragma unroll
            for (int q = 0; q < 4; ++q) { a[q] = f2bf(st0[q]); b[q] = f2bf(st1[q]); }
            short* base = Abuf[buf ^ 1];
            *(bf16x4*)&base[dswz0] = a;
            *(bf16x4*)&base[dswz1] = b;
            if constexpr (V != 4) __syncthreads();   // no-barrier probe
        }
    }

    if constexpr (V == 0) {
        float bv[4];
        #pragma unroll
        for (int nf = 0; nf < 4; ++nf)
            bv[nf] = bias[s * NMAXD + w * 64 + nf * 16 + lrow];
        #pragma unroll
        for (int mf = 0; mf < 4; ++mf) {
            #pragma unroll
            for (int q = 0; q < 4; ++q) {
                const int r = mf * 16 + lgr * 4 + q;
                if (r < rows_here) {
                    float* orow = out + (size_t)aidx[r] * NMAXD + w * 64 + lrow;
                    #pragma unroll
                    for (int nf = 0; nf < 4; ++nf)
                        orow[nf * 16] = acc[mf][nf][q] + bv[nf];
                }
            }
        }
    } else {
        // keep everything live without touching d_out (rule #17)
        float t = 0.f;
        #pragma unroll
        for (int mf = 0; mf < 4; ++mf)
            #pragma unroll
            for (int nf = 0; nf < 4; ++nf)
                t += acc[mf][nf][0] + acc[mf][nf][1] + acc[mf][nf][2] + acc[mf][nf][3];
        asm volatile("" :: "v"(t));
    }
}

extern "C" void kernel_launch(void* const* d_in, const int* in_sizes, int n_in,
                              void* d_out, int out_size, void* d_ws, size_t ws_size,
                              hipStream_t stream) {
    const float* rho = (const float*)d_in[0];
    const float* W   = (const float*)d_in[1];
    const float* b   = (const float*)d_in[2];
    const int*   sym = (const int*)d_in[3];
    float* out = (float*)d_out;

    int*   counts = (int*)d_ws;
    int*   lists  = (int*)((char*)d_ws + 1024);
    short* Wp     = (short*)((char*)d_ws + 1024 + (size_t)NSPE * NTA * 4);

    pack_w_kernel<<<(NSPE * DIM_O * NMAXD) / 256, 256, 0, stream>>>(W, Wp, counts);
    build_lists_kernel<<<NTA / 256, 256, 0, stream>>>(sym, counts, lists);

    const int grid = NSPE * (NTA / BM);
    gemm_tpl<0><<<grid, 512, 0, stream>>>(rho, Wp, b, counts, lists, out);  // real
    gemm_tpl<1><<<grid, 512, 0, stream>>>(rho, Wp, b, counts, lists, out);  // no-store
    gemm_tpl<2><<<grid, 512, 0, stream>>>(rho, Wp, b, counts, lists, out);  // +linear gather
    gemm_tpl<3><<<grid, 512, 0, stream>>>(rho, Wp, b, counts, lists, out);  // +const B
    gemm_tpl<4><<<grid, 512, 0, stream>>>(rho, Wp, b, counts, lists, out);  // +no barriers
}

// Round 6
// 126.812 us; speedup vs baseline: 2.3011x; 2.3011x over previous
//
#include <hip/hip_runtime.h>

// Species-routed expert Linear as a bucketed grouped GEMM.
//   out[a] = rho[a] @ W[sym[a]] + b[sym[a]]   (NTA=65536, K=N=512, 4 species)
// R6: ablation (R5) showed a 5x interaction stall: in-loop random A-gather x
//     vmcnt-ordering vs B loads x per-step barrier convoy. Fix: hoist the
//     ENTIRE A-tile gather into the prologue (64 rows x 512 k as bf16 = 64 KB
//     LDS, one barrier), then a barrier-free K-loop touching only read-only
//     LDS + L2-resident B + MFMA. BM=64 x BN=512, 8 waves, 2 blocks/CU.

#define NTA   65536
#define DIM_O 512
#define NMAXD 512
#define NSPE  4
#define BM    64
#define BK    64

typedef __attribute__((ext_vector_type(4))) float  f32x4;
typedef __attribute__((ext_vector_type(8))) short  bf16x8;
typedef __attribute__((ext_vector_type(4))) short  bf16x4;

__device__ __forceinline__ short f2bf(float f) {
    unsigned u = __builtin_bit_cast(unsigned, f);
    u += 0x7FFFu + ((u >> 16) & 1u);
    return (short)(u >> 16);
}

__global__ void build_lists_kernel(const int* __restrict__ sym,
                                   int* __restrict__ counts,
                                   int* __restrict__ lists) {
    int i = blockIdx.x * 256 + threadIdx.x;
    int s = sym[i];
    int lane = threadIdx.x & 63;
    #pragma unroll
    for (int spe = 0; spe < NSPE; ++spe) {
        unsigned long long m = __ballot(s == spe);
        if (m == 0ull) continue;
        int leader = __ffsll(m) - 1;
        int base = 0;
        if (lane == leader) base = atomicAdd(&counts[spe], __popcll(m));
        base = __shfl(base, leader);
        if (s == spe) {
            int pos = __popcll(m & ((1ull << lane) - 1ull));
            lists[spe * NTA + base + pos] = i;
        }
    }
}

// Pack W[s][k][n] (fp32) -> bf16 MFMA-B fragment layout; also zeroes counts
// (launched BEFORE build_lists on the same stream).
__global__ void pack_w_kernel(const float* __restrict__ W, short* __restrict__ Wp,
                              int* __restrict__ counts) {
    if (blockIdx.x == 0 && threadIdx.x < NSPE) counts[threadIdx.x] = 0;
    int idx = blockIdx.x * 256 + threadIdx.x;
    int j  = idx & 7;
    int l  = (idx >> 3) & 63;
    int nb = (idx >> 9) & 31;
    int kb = (idx >> 14) & 15;
    int s  = idx >> 18;
    int k = kb * 32 + (l >> 4) * 8 + j;
    int n = nb * 16 + (l & 15);
    Wp[idx] = f2bf(W[((size_t)s * DIM_O + k) * NMAXD + n]);
}

// LDS A layout (full K): 16B slot = chunk*64 + (row ^ ((chunk&3)<<1)),
// chunk = k-floats [8c, 8c+8), c in 0..63. Same XOR swizzle as R4/R5
// (measured 0 conflicts on both sides).
__global__ __launch_bounds__(512, 4)   // min 4 waves/SIMD -> VGPR<=128, 2 blk/CU
void gemm_kernel(const float* __restrict__ rho,
                 const short* __restrict__ Wp,
                 const float* __restrict__ bias,
                 const int*  __restrict__ counts,
                 const int*  __restrict__ lists,
                 float* __restrict__ out)
{
    const int s   = blockIdx.x & 3;
    const int mb  = blockIdx.x >> 2;
    const int cnt = counts[s];
    const int row0 = mb * BM;
    if (row0 >= cnt) return;
    int rows_here = cnt - row0; if (rows_here > BM) rows_here = BM;

    __shared__ int aidx[BM];
    __shared__ __align__(16) short Abuf[64 * 64 * 8];   // 64 KB, full A tile

    const int tid  = threadIdx.x;
    const int lane = tid & 63;
    const int w    = tid >> 6;            // wave 0..7 owns cols [w*64, w*64+64)
    const int lrow = lane & 15;
    const int lgr  = lane >> 4;

    if (tid < BM)
        aidx[tid] = lists[s * NTA + row0 + ((tid < rows_here) ? tid : 0)];
    __syncthreads();

    // ---- prologue: gather the WHOLE A tile (once), convert, stage to LDS ----
    // thread t -> row t>>3; 8 consecutive lanes cover 128 B contiguous per
    // 32-float group (requests merge). 16 x f32x4 loads per thread.
    {
        const int srow  = tid >> 3;
        const int scol8 = tid & 7;
        const float* gsrc = rho + (size_t)aidx[srow] * DIM_O + scol8 * 4;
        const int c0   = scol8 >> 1;
        const int roww = srow ^ ((c0 & 3) << 1);        // chunk&3 == c0 for all r
        const int dof  = (scol8 & 1) * 4;

        f32x4 v[16];
        #pragma unroll
        for (int r = 0; r < 16; ++r)
            v[r] = *(const f32x4*)(gsrc + r * 32);
        #pragma unroll
        for (int r = 0; r < 16; ++r) {
            bf16x4 a;
            #pragma unroll
            for (int q = 0; q < 4; ++q) a[q] = f2bf(v[r][q]);
            *(bf16x4*)&Abuf[((r * 4 + c0) * 64 + roww) * 8 + dof] = a;
        }
    }
    __syncthreads();

    // ---- barrier-free K-loop: read-only LDS + L2-resident B + MFMA ----
    const short* wbase = Wp + ((size_t)s * 512 + w * 4) * 512 + lane * 8;

    f32x4 acc[4][4];
    #pragma unroll
    for (int m = 0; m < 4; ++m)
        #pragma unroll
        for (int n = 0; n < 4; ++n) acc[m][n] = (f32x4)0.0f;

    #pragma unroll
    for (int kt = 0; kt < 8; ++kt) {
        bf16x8 bfr[2][4];
        #pragma unroll
        for (int ks = 0; ks < 2; ++ks)
            #pragma unroll
            for (int nf = 0; nf < 4; ++nf)
                bfr[ks][nf] = *(const bf16x8*)
                    (wbase + (size_t)((kt * 2 + ks) * 32 + nf) * 512);
        #pragma unroll
        for (int ks = 0; ks < 2; ++ks) {
            #pragma unroll
            for (int mf = 0; mf < 4; ++mf) {
                const int c = kt * 8 + ks * 4 + lgr;
                const int r = (mf * 16 + lrow) ^ ((lgr & 3) << 1);
                const bf16x8 afrag = *(const bf16x8*)&Abuf[(c * 64 + r) * 8];
                #pragma unroll
                for (int nf = 0; nf < 4; ++nf)
                    acc[mf][nf] = __builtin_amdgcn_mfma_f32_16x16x32_bf16(
                        afrag, bfr[ks][nf], acc[mf][nf], 0, 0, 0);
            }
        }
    }

    // ---- epilogue: bias + per-row store (16 lanes x 64 B contiguous) ----
    float bv[4];
    #pragma unroll
    for (int nf = 0; nf < 4; ++nf)
        bv[nf] = bias[s * NMAXD + w * 64 + nf * 16 + lrow];
    #pragma unroll
    for (int mf = 0; mf < 4; ++mf) {
        #pragma unroll
        for (int q = 0; q < 4; ++q) {
            const int r = mf * 16 + lgr * 4 + q;
            if (r < rows_here) {
                float* orow = out + (size_t)aidx[r] * NMAXD + w * 64 + lrow;
                #pragma unroll
                for (int nf = 0; nf < 4; ++nf)
                    orow[nf * 16] = acc[mf][nf][q] + bv[nf];
            }
        }
    }
}

extern "C" void kernel_launch(void* const* d_in, const int* in_sizes, int n_in,
                              void* d_out, int out_size, void* d_ws, size_t ws_size,
                              hipStream_t stream) {
    const float* rho = (const float*)d_in[0];
    const float* W   = (const float*)d_in[1];
    const float* b   = (const float*)d_in[2];
    const int*   sym = (const int*)d_in[3];
    float* out = (float*)d_out;

    int*   counts = (int*)d_ws;
    int*   lists  = (int*)((char*)d_ws + 1024);
    short* Wp     = (short*)((char*)d_ws + 1024 + (size_t)NSPE * NTA * 4);

    pack_w_kernel<<<(NSPE * DIM_O * NMAXD) / 256, 256, 0, stream>>>(W, Wp, counts);
    build_lists_kernel<<<NTA / 256, 256, 0, stream>>>(sym, counts, lists);
    gemm_kernel<<<NSPE * (NTA / BM), 512, 0, stream>>>(rho, Wp, b, counts, lists, out);
}